// Round 2
// baseline (48844.955 us; speedup 1.0000x reference)
//
#include <hip/hip_runtime.h>
#include <cmath>

// Problem constants: B=64, S=2048, I=512, H=512
#define BB 64
#define SS 2048
#define II 512
#define HH 512

// ---------------------------------------------------------------------------
// Kernel A: xproj[m][n] = sum_k x[m][k] * Wx[n][k] + bh[n]   (fp32 NT GEMM)
// ---------------------------------------------------------------------------
__global__ __launch_bounds__(256) void xproj_kernel(
    const float* __restrict__ A,    // x: (M, 512)
    const float* __restrict__ W,    // Wx: (512, 512) row-major (N x K)
    const float* __restrict__ bias, // bh: (512,)
    float* __restrict__ C)          // out: (M, 512)
{
    __shared__ float Ast[16][68];
    __shared__ float Bst[16][68];

    const int tid = threadIdx.x;
    const long m0 = (long)blockIdx.x * 64;
    const int n0 = blockIdx.y * 64;
    const int row = tid >> 2;
    const int kq = (tid & 3) << 2;
    const int tx = tid & 15;
    const int ty = tid >> 4;

    float acc[4][4] = {};

    for (int k0 = 0; k0 < 512; k0 += 16) {
        float4 a4 = *(const float4*)&A[(m0 + row) * 512 + k0 + kq];
        float4 b4 = *(const float4*)&W[(long)(n0 + row) * 512 + k0 + kq];
        __syncthreads();
        Ast[kq + 0][row] = a4.x; Ast[kq + 1][row] = a4.y;
        Ast[kq + 2][row] = a4.z; Ast[kq + 3][row] = a4.w;
        Bst[kq + 0][row] = b4.x; Bst[kq + 1][row] = b4.y;
        Bst[kq + 2][row] = b4.z; Bst[kq + 3][row] = b4.w;
        __syncthreads();
#pragma unroll
        for (int kk = 0; kk < 16; ++kk) {
            float4 av = *(const float4*)&Ast[kk][ty << 2];
            float4 bv = *(const float4*)&Bst[kk][tx << 2];
            acc[0][0] += av.x * bv.x; acc[0][1] += av.x * bv.y;
            acc[0][2] += av.x * bv.z; acc[0][3] += av.x * bv.w;
            acc[1][0] += av.y * bv.x; acc[1][1] += av.y * bv.y;
            acc[1][2] += av.y * bv.z; acc[1][3] += av.y * bv.w;
            acc[2][0] += av.z * bv.x; acc[2][1] += av.z * bv.y;
            acc[2][2] += av.z * bv.z; acc[2][3] += av.z * bv.w;
            acc[3][0] += av.w * bv.x; acc[3][1] += av.w * bv.y;
            acc[3][2] += av.w * bv.z; acc[3][3] += av.w * bv.w;
        }
    }

    float4 bias4 = *(const float4*)&bias[n0 + (tx << 2)];
#pragma unroll
    for (int a = 0; a < 4; ++a) {
        float4 o;
        o.x = acc[a][0] + bias4.x;
        o.y = acc[a][1] + bias4.y;
        o.z = acc[a][2] + bias4.z;
        o.w = acc[a][3] + bias4.w;
        *(float4*)&C[(m0 + (ty << 2) + a) * 512 + n0 + (tx << 2)] = o;
    }
}

// ---------------------------------------------------------------------------
// Pack Wh into per-thread-slab, coalesced-stream layout in d_ws (1 MB):
//   slab of thread t: rows (t&~7)+jj (jj=0..7), cols (t&7)*64 + kq*4.. (kq=0..15)
//   wp[(kq*8+jj)*512 + t] = Wh[(t&~7)+jj][(t&7)*64 + kq*4 .. +3]
// Consecutive t -> consecutive 16B: each wave-inst in the rnn reads 1 KB
// contiguous. All 64 blocks read the SAME 512 KB/step -> L2-resident per XCD.
// ---------------------------------------------------------------------------
__global__ __launch_bounds__(256) void pack_wh(const float* __restrict__ Wh,
                                               float4* __restrict__ wp) {
    int id = blockIdx.x * 256 + threadIdx.x;  // 0..65535
    int t = id & 511;
    int idx = id >> 9;                        // 0..127 = kq*8 + jj
    int kq = idx >> 3, jj = idx & 7;
    int row = (t & ~7) + jj;
    int col = (t & 7) * 64 + kq * 4;
    wp[idx * 512 + t] = *(const float4*)&Wh[row * 512 + col];
}

// ---------------------------------------------------------------------------
// Kernel B (fast): one block per batch, 512 threads.
// Thread t: j-octet (t&~7)+0..7  x  k-slice (t&7)*64..+63. 128 float4 weight
// loads/step, 2-stage software pipeline, 512 fmaf. Butterfly reduce over the
// 8 k-slices (lanes xor 1/2/4); lane finalizes j == t (coalesced xp/out).
// h double-buffered in LDS, swizzled [quad c][slice s] so reads are
// conflict-free broadcasts. One barrier per step. xp prefetched 1 step ahead.
// ---------------------------------------------------------------------------
__global__ __launch_bounds__(512, 2) void rnn_fast(
    float* __restrict__ out,          // (B,S,H): in = xproj+bias, out = h_t
    const float4* __restrict__ wp,    // packed Wh (1 MB)
    const float* __restrict__ h0,     // (B,H)
    float* __restrict__ hlast)        // (B,H)
{
    __shared__ float4 hswz[2][128];   // [buf][c*8 + s], c=0..15 quad, s=0..7 slice

    const int b = blockIdx.x;
    const int t = threadIdx.x;
    const int s = t & 7;              // k-slice owned by this thread
    // swizzled write coords for h[j==t]: k-index K=t -> slice t>>6, quad (t>>2)&15, pos t&3
    const int c_w = (t >> 2) & 15;
    const int s_w = t >> 6;
    const int p_w = t & 3;

    ((float*)&hswz[0][c_w * 8 + s_w])[p_w] = h0[b * HH + t];

    float* po = out + (size_t)b * SS * HH + t;
    float xp_cur = __builtin_nontemporal_load(po);   // xp[b][0][t]
    __syncthreads();

    float hn = 0.0f;
    for (int ts = 0; ts < SS; ++ts) {
        const int cur = ts & 1;
        const float4* hb = hswz[cur];

        // prefetch next step's xp (for ts==SS-1 this reads the next batch's
        // region / hlast area -> still inside d_out, value discarded)
        float xp_next = __builtin_nontemporal_load(po + (size_t)(ts + 1) * HH);

        float acc[8];
#pragma unroll
        for (int jj = 0; jj < 8; ++jj) acc[jj] = 0.0f;

        float4 w[2][8];
        float4 hq[2];
#pragma unroll
        for (int jj = 0; jj < 8; ++jj) w[0][jj] = wp[jj * 512 + t];
        hq[0] = hb[s];

#pragma unroll
        for (int kq = 0; kq < 16; ++kq) {
            const int cb = kq & 1, nb = cb ^ 1;
            if (kq < 15) {
#pragma unroll
                for (int jj = 0; jj < 8; ++jj)
                    w[nb][jj] = wp[((kq + 1) * 8 + jj) * 512 + t];
                hq[nb] = hb[(kq + 1) * 8 + s];
            }
            const float4 h4 = hq[cb];
#pragma unroll
            for (int jj = 0; jj < 8; ++jj) {
                float a = acc[jj];
                a = fmaf(w[cb][jj].x, h4.x, a);
                a = fmaf(w[cb][jj].y, h4.y, a);
                a = fmaf(w[cb][jj].z, h4.z, a);
                a = fmaf(w[cb][jj].w, h4.w, a);
                acc[jj] = a;
            }
        }

        // butterfly sum over the 8 k-slices (lanes xor 1,2,4 within octet)
#pragma unroll
        for (int m = 1; m < 8; m <<= 1) {
#pragma unroll
            for (int jj = 0; jj < 8; ++jj)
                acc[jj] += __shfl_xor(acc[jj], m, 64);
        }
        // pick acc[s] without dynamic indexing (avoid scratch): 3-level mux
        float a01 = (s & 1) ? acc[1] : acc[0];
        float a23 = (s & 1) ? acc[3] : acc[2];
        float a45 = (s & 1) ? acc[5] : acc[4];
        float a67 = (s & 1) ? acc[7] : acc[6];
        float a03 = (s & 2) ? a23 : a01;
        float a47 = (s & 2) ? a67 : a45;
        float asum = (s & 4) ? a47 : a03;

        hn = tanhf(asum + xp_cur);   // bias already folded into xp

        __builtin_nontemporal_store(hn, po + (size_t)ts * HH);
        ((float*)&hswz[cur ^ 1][c_w * 8 + s_w])[p_w] = hn;
        __syncthreads();
        xp_cur = xp_next;
    }

    hlast[b * HH + t] = hn;
}

// ---------------------------------------------------------------------------
// Fallback recurrence (round-1 style) if ws is too small for the pack.
// ---------------------------------------------------------------------------
__global__ __launch_bounds__(512) void rnn_kernel_fallback(
    float* __restrict__ out, const float* __restrict__ Whx,
    const float* __restrict__ h0, float* __restrict__ hlast)
{
    __shared__ float h[HH];
    const int b = blockIdx.x;
    const int j = threadIdx.x;
    h[j] = h0[b * HH + j];
    __syncthreads();
    float* po = out + (long)b * SS * HH + j;
    for (int ts = 0; ts < SS; ++ts) {
        float acc = po[(long)ts * HH];
#pragma unroll 4
        for (int k = 0; k < HH; k += 4) {
            float4 hv = *(const float4*)&h[k];
            acc += Whx[j * HH + (k + 0)] * hv.x;
            acc += Whx[j * HH + (k + 1)] * hv.y;
            acc += Whx[j * HH + (k + 2)] * hv.z;
            acc += Whx[j * HH + (k + 3)] * hv.w;
        }
        float hnv = tanhf(acc);
        __syncthreads();
        h[j] = hnv;
        po[(long)ts * HH] = hnv;
        __syncthreads();
    }
    hlast[b * HH + j] = h[j];
}

extern "C" void kernel_launch(void* const* d_in, const int* in_sizes, int n_in,
                              void* d_out, int out_size, void* d_ws, size_t ws_size,
                              hipStream_t stream) {
    const float* x  = (const float*)d_in[0];
    const float* h0 = (const float*)d_in[1];
    const float* Wx = (const float*)d_in[2];
    const float* Wh = (const float*)d_in[3];
    const float* bh = (const float*)d_in[4];

    float* out = (float*)d_out;
    float* hlast = out + (long)BB * SS * HH;

    dim3 gA(BB * SS / 64, HH / 64);
    xproj_kernel<<<gA, 256, 0, stream>>>(x, Wx, bh, out);

    const size_t packBytes = (size_t)HH * HH * sizeof(float);  // 1 MB
    if (ws_size >= packBytes) {
        float4* wp = (float4*)d_ws;
        pack_wh<<<256, 256, 0, stream>>>(Wh, wp);
        rnn_fast<<<BB, HH, 0, stream>>>(out, wp, h0, hlast);
    } else {
        rnn_kernel_fallback<<<BB, HH, 0, stream>>>(out, Wh, h0, hlast);
    }
}

// Round 3
// 41505.899 us; speedup vs baseline: 1.1768x; 1.1768x over previous
//
#include <hip/hip_runtime.h>
#include <cmath>

// Problem constants: B=64, S=2048, I=512, H=512
#define BB 64
#define SS 2048
#define II 512
#define HH 512

// ---------------------------------------------------------------------------
// Kernel A: xproj[m][n] = sum_k x[m][k] * Wx[n][k] + bh[n]   (fp32 NT GEMM)
// ---------------------------------------------------------------------------
__global__ __launch_bounds__(256) void xproj_kernel(
    const float* __restrict__ A,    // x: (M, 512)
    const float* __restrict__ W,    // Wx: (512, 512) row-major (N x K)
    const float* __restrict__ bias, // bh: (512,)
    float* __restrict__ C)          // out: (M, 512)
{
    __shared__ float Ast[16][68];
    __shared__ float Bst[16][68];

    const int tid = threadIdx.x;
    const long m0 = (long)blockIdx.x * 64;
    const int n0 = blockIdx.y * 64;
    const int row = tid >> 2;
    const int kq = (tid & 3) << 2;
    const int tx = tid & 15;
    const int ty = tid >> 4;

    float acc[4][4] = {};

    for (int k0 = 0; k0 < 512; k0 += 16) {
        float4 a4 = *(const float4*)&A[(m0 + row) * 512 + k0 + kq];
        float4 b4 = *(const float4*)&W[(long)(n0 + row) * 512 + k0 + kq];
        __syncthreads();
        Ast[kq + 0][row] = a4.x; Ast[kq + 1][row] = a4.y;
        Ast[kq + 2][row] = a4.z; Ast[kq + 3][row] = a4.w;
        Bst[kq + 0][row] = b4.x; Bst[kq + 1][row] = b4.y;
        Bst[kq + 2][row] = b4.z; Bst[kq + 3][row] = b4.w;
        __syncthreads();
#pragma unroll
        for (int kk = 0; kk < 16; ++kk) {
            float4 av = *(const float4*)&Ast[kk][ty << 2];
            float4 bv = *(const float4*)&Bst[kk][tx << 2];
            acc[0][0] += av.x * bv.x; acc[0][1] += av.x * bv.y;
            acc[0][2] += av.x * bv.z; acc[0][3] += av.x * bv.w;
            acc[1][0] += av.y * bv.x; acc[1][1] += av.y * bv.y;
            acc[1][2] += av.y * bv.z; acc[1][3] += av.y * bv.w;
            acc[2][0] += av.z * bv.x; acc[2][1] += av.z * bv.y;
            acc[2][2] += av.z * bv.z; acc[2][3] += av.z * bv.w;
            acc[3][0] += av.w * bv.x; acc[3][1] += av.w * bv.y;
            acc[3][2] += av.w * bv.z; acc[3][3] += av.w * bv.w;
        }
    }

    float4 bias4 = *(const float4*)&bias[n0 + (tx << 2)];
#pragma unroll
    for (int a = 0; a < 4; ++a) {
        float4 o;
        o.x = acc[a][0] + bias4.x;
        o.y = acc[a][1] + bias4.y;
        o.z = acc[a][2] + bias4.z;
        o.w = acc[a][3] + bias4.w;
        *(float4*)&C[(m0 + (ty << 2) + a) * 512 + n0 + (tx << 2)] = o;
    }
}

// ---------------------------------------------------------------------------
// Transpose Wh (512x512) -> WhT[k*512 + j] in d_ws.
// ---------------------------------------------------------------------------
__global__ __launch_bounds__(256) void transpose512(
    const float* __restrict__ in, float* __restrict__ out)
{
    __shared__ float tile[32][33];
    int x = blockIdx.x * 32 + threadIdx.x;
    int y = blockIdx.y * 32 + threadIdx.y;
#pragma unroll
    for (int i = 0; i < 32; i += 8)
        tile[threadIdx.y + i][threadIdx.x] = in[(y + i) * 512 + x];
    __syncthreads();
    x = blockIdx.y * 32 + threadIdx.x;
    y = blockIdx.x * 32 + threadIdx.y;
#pragma unroll
    for (int i = 0; i < 32; i += 8)
        out[(y + i) * 512 + x] = tile[threadIdx.x][threadIdx.y + i];
}

// ---------------------------------------------------------------------------
// Kernel B (v3): 32 blocks, each owns a PAIR of batches (weight reuse: every
// WhT float4 feeds 8 FMAs). 512 threads = 128 j-quads x 4 k-slices.
// Thread (jq, s): j = jq*4..+3, k in [s*128, s*128+128).
// Weight access is k-major, j-coalesced (the R1 pattern that cached at 99.9%):
// per wave-instr, 4 contiguous 256B segments; all blocks march the same 1 MB
// stream in the same order -> L2-resident. 4-stage weight pipeline (dwordx4),
// h broadcast from padded LDS slices (132-float stride -> conflict-free),
// butterfly reduce over the 4 k-slices (lanes xor 1,2), one barrier/step.
// out[] holds xproj+bias on entry; overwritten in place with h_t.
// ---------------------------------------------------------------------------
__global__ __launch_bounds__(512) void rnn_v3(
    float* __restrict__ out,        // (B,S,H)
    const float* __restrict__ wt,   // WhT: [k*512 + j]
    const float* __restrict__ h0,   // (B,H)
    float* __restrict__ hlast)      // (B,H)
{
    // [buf][batch][slice*132 + pos]; 132 = 128 + 4 pad (conflict-free reads)
    __shared__ __align__(16) float hsm[2][2][528];

    const int bp  = blockIdx.x;       // batch pair
    const int b0  = bp * 2, b1 = bp * 2 + 1;
    const int tid = threadIdx.x;
    const int s   = tid & 3;          // k-slice
    const int jq  = tid >> 2;         // j-quad
    const int wslice = tid >> 7;      // h-write slice for j == tid
    const int wpos   = tid & 127;

    hsm[0][0][wslice * 132 + wpos] = h0[b0 * HH + tid];
    hsm[0][1][wslice * 132 + wpos] = h0[b1 * HH + tid];

    const float* wbase = wt + (size_t)(s * 128) * HH + jq * 4;
    float* po0 = out + (size_t)b0 * SS * HH + tid;
    float* po1 = out + (size_t)b1 * SS * HH + tid;

    float xp0 = po0[0];
    float xp1 = po1[0];
    __syncthreads();

    // weight pipeline: 4 stages of 4 float4; preload quads 0,1
    float4 w[4][4];
#pragma unroll
    for (int q0 = 0; q0 < 2; ++q0)
#pragma unroll
        for (int u = 0; u < 4; ++u)
            w[q0][u] = *(const float4*)(wbase + (size_t)(q0 * 4 + u) * HH);

    // h pipeline: 2 stages per batch; preload quad 0 from buffer 0
    float4 h4a[2], h4b[2];
    h4a[0] = *(const float4*)&hsm[0][0][s * 132];
    h4b[0] = *(const float4*)&hsm[0][1][s * 132];

    float hn0 = 0.0f, hn1 = 0.0f;

    for (int ts = 0; ts < SS; ++ts) {
        const int cur = ts & 1, nxt = cur ^ 1;
        const float* hcur0 = &hsm[cur][0][s * 132];
        const float* hcur1 = &hsm[cur][1][s * 132];

        // prefetch next step's xp early (overlaps the whole q-loop)
        const int tn = (ts < SS - 1) ? ts + 1 : ts;
        float xpn0 = po0[(size_t)tn * HH];
        float xpn1 = po1[(size_t)tn * HH];

        float acc0[4] = {0.f, 0.f, 0.f, 0.f};
        float acc1[4] = {0.f, 0.f, 0.f, 0.f};

#pragma unroll
        for (int q = 0; q < 32; ++q) {
            const int st = q & 3;
            const int hs = q & 1;
            // prefetch weight quad (q+2)&31 (weights identical every step, so
            // wrapping naturally preloads next step's quads 0,1)
            {
                const int pq = (q + 2) & 31;
                const int ps = (q + 2) & 3;
#pragma unroll
                for (int u = 0; u < 4; ++u)
                    w[ps][u] = *(const float4*)(wbase + (size_t)(pq * 4 + u) * HH);
            }
            if (q < 31) {
                h4a[(q + 1) & 1] = *(const float4*)&hcur0[(q + 1) * 4];
                h4b[(q + 1) & 1] = *(const float4*)&hcur1[(q + 1) * 4];
            }
            const float4 ha = h4a[hs];
            const float4 hbq = h4b[hs];
#pragma unroll
            for (int u = 0; u < 4; ++u) {
                const float4 wv = w[st][u];
                const float hau = (u == 0) ? ha.x : (u == 1) ? ha.y : (u == 2) ? ha.z : ha.w;
                const float hbu = (u == 0) ? hbq.x : (u == 1) ? hbq.y : (u == 2) ? hbq.z : hbq.w;
                acc0[0] = fmaf(wv.x, hau, acc0[0]);
                acc0[1] = fmaf(wv.y, hau, acc0[1]);
                acc0[2] = fmaf(wv.z, hau, acc0[2]);
                acc0[3] = fmaf(wv.w, hau, acc0[3]);
                acc1[0] = fmaf(wv.x, hbu, acc1[0]);
                acc1[1] = fmaf(wv.y, hbu, acc1[1]);
                acc1[2] = fmaf(wv.z, hbu, acc1[2]);
                acc1[3] = fmaf(wv.w, hbu, acc1[3]);
            }
        }

        // butterfly sum over the 4 k-slices (lanes xor 1, 2 inside each quad)
#pragma unroll
        for (int m = 1; m <= 2; m <<= 1) {
#pragma unroll
            for (int jj = 0; jj < 4; ++jj) {
                acc0[jj] += __shfl_xor(acc0[jj], m, 64);
                acc1[jj] += __shfl_xor(acc1[jj], m, 64);
            }
        }
        // lane s picks component s (j = jq*4 + s == tid)
        float t00 = (s & 1) ? acc0[1] : acc0[0];
        float t01 = (s & 1) ? acc0[3] : acc0[2];
        float sum0 = (s & 2) ? t01 : t00;
        float t10 = (s & 1) ? acc1[1] : acc1[0];
        float t11 = (s & 1) ? acc1[3] : acc1[2];
        float sum1 = (s & 2) ? t11 : t10;

        hn0 = tanhf(sum0 + xp0);
        hn1 = tanhf(sum1 + xp1);

        po0[(size_t)ts * HH] = hn0;
        po1[(size_t)ts * HH] = hn1;
        hsm[nxt][0][wslice * 132 + wpos] = hn0;
        hsm[nxt][1][wslice * 132 + wpos] = hn1;
        __syncthreads();

        // reload h stage 0 from the freshly-written buffer
        h4a[0] = *(const float4*)&hsm[nxt][0][s * 132];
        h4b[0] = *(const float4*)&hsm[nxt][1][s * 132];
        xp0 = xpn0;
        xp1 = xpn1;
    }

    hlast[b0 * HH + tid] = hn0;
    hlast[b1 * HH + tid] = hn1;
}

// ---------------------------------------------------------------------------
// Fallback recurrence if ws too small for WhT.
// ---------------------------------------------------------------------------
__global__ __launch_bounds__(512) void rnn_kernel_fallback(
    float* __restrict__ out, const float* __restrict__ Whx,
    const float* __restrict__ h0, float* __restrict__ hlast)
{
    __shared__ float h[HH];
    const int b = blockIdx.x;
    const int j = threadIdx.x;
    h[j] = h0[b * HH + j];
    __syncthreads();
    float* po = out + (long)b * SS * HH + j;
    for (int ts = 0; ts < SS; ++ts) {
        float acc = po[(long)ts * HH];
#pragma unroll 4
        for (int k = 0; k < HH; k += 4) {
            float4 hv = *(const float4*)&h[k];
            acc += Whx[j * HH + (k + 0)] * hv.x;
            acc += Whx[j * HH + (k + 1)] * hv.y;
            acc += Whx[j * HH + (k + 2)] * hv.z;
            acc += Whx[j * HH + (k + 3)] * hv.w;
        }
        float hnv = tanhf(acc);
        __syncthreads();
        h[j] = hnv;
        po[(long)ts * HH] = hnv;
        __syncthreads();
    }
    hlast[b * HH + j] = h[j];
}

extern "C" void kernel_launch(void* const* d_in, const int* in_sizes, int n_in,
                              void* d_out, int out_size, void* d_ws, size_t ws_size,
                              hipStream_t stream) {
    const float* x  = (const float*)d_in[0];
    const float* h0 = (const float*)d_in[1];
    const float* Wx = (const float*)d_in[2];
    const float* Wh = (const float*)d_in[3];
    const float* bh = (const float*)d_in[4];

    float* out = (float*)d_out;
    float* hlast = out + (long)BB * SS * HH;

    dim3 gA(BB * SS / 64, HH / 64);
    xproj_kernel<<<gA, 256, 0, stream>>>(x, Wx, bh, out);

    const size_t whBytes = (size_t)HH * HH * sizeof(float);  // 1 MB
    if (ws_size >= whBytes) {
        float* WhT = (float*)d_ws;
        transpose512<<<dim3(16, 16), dim3(32, 8), 0, stream>>>(Wh, WhT);
        rnn_v3<<<BB / 2, 512, 0, stream>>>(out, WhT, h0, hlast);
    } else {
        rnn_kernel_fallback<<<BB, HH, 0, stream>>>(out, Wh, h0, hlast);
    }
}